// Round 4
// baseline (5300.049 us; speedup 1.0000x reference)
//
#include <hip/hip_runtime.h>

#define B_   32
#define T_   2048
#define DIN  128
#define H_   256
#define DOUT 256

typedef _Float16 h2_t __attribute__((ext_vector_type(2)));

__device__ __forceinline__ float fdot2a(unsigned int a, unsigned int b, float c) {
#if defined(__has_builtin) && __has_builtin(__builtin_amdgcn_fdot2)
  return __builtin_amdgcn_fdot2(__builtin_bit_cast(h2_t, a),
                                __builtin_bit_cast(h2_t, b), c, false);
#else
  h2_t x = __builtin_bit_cast(h2_t, a), y = __builtin_bit_cast(h2_t, b);
  return c + (float)x[0] * (float)y[0] + (float)x[1] * (float)y[1];
#endif
}

// ---------------- Kernel 1: G = x @ [Wz|Wr|Wh] + [bz|br|bh]  (fp16 out) ----
__global__ __launch_bounds__(256) void k_gates(
    const float* __restrict__ x,
    const float* __restrict__ Wz, const float* __restrict__ Wr,
    const float* __restrict__ Wh,
    const float* __restrict__ bz, const float* __restrict__ br,
    const float* __restrict__ bh,
    _Float16* __restrict__ Gzr,   // [BT][512] gates z,r   (lives in d_out ys region)
    _Float16* __restrict__ Gh)    // [BT][256] gate h      (lives in ws)
{
  __shared__ __align__(16) float sx[32][DIN];
  const int gate = blockIdx.y;
  const float* W = (gate == 0) ? Wz : (gate == 1) ? Wr : Wh;
  const float* bias = (gate == 0) ? bz : (gate == 1) ? br : bh;
  const int row0 = blockIdx.x * 32;
  const int tid = threadIdx.x;

  const float4* xg = (const float4*)(x + (size_t)row0 * DIN);
  float4* sx4 = (float4*)&sx[0][0];
#pragma unroll
  for (int m = 0; m < 4; ++m) sx4[tid + 256 * m] = xg[tid + 256 * m];
  __syncthreads();

  const int j = tid;
  const float bj = bias[j];
  float acc[32];
#pragma unroll
  for (int i = 0; i < 32; ++i) acc[i] = 0.f;

#pragma unroll 2
  for (int k4 = 0; k4 < DIN / 4; ++k4) {
    float w0 = W[(size_t)(4 * k4 + 0) * H_ + j];
    float w1 = W[(size_t)(4 * k4 + 1) * H_ + j];
    float w2 = W[(size_t)(4 * k4 + 2) * H_ + j];
    float w3 = W[(size_t)(4 * k4 + 3) * H_ + j];
#pragma unroll
    for (int i = 0; i < 32; ++i) {
      float4 xv = *(const float4*)&sx[i][4 * k4];
      acc[i] = fmaf(xv.x, w0, acc[i]);
      acc[i] = fmaf(xv.y, w1, acc[i]);
      acc[i] = fmaf(xv.z, w2, acc[i]);
      acc[i] = fmaf(xv.w, w3, acc[i]);
    }
  }

  if (gate < 2) {
    _Float16* Gp = Gzr + (size_t)row0 * 512 + gate * H_ + j;
#pragma unroll
    for (int i = 0; i < 32; ++i) Gp[(size_t)i * 512] = (_Float16)(acc[i] + bj);
  } else {
    _Float16* Gp = Gh + (size_t)row0 * H_ + j;
#pragma unroll
    for (int i = 0; i < 32; ++i) Gp[(size_t)i * H_] = (_Float16)(acc[i] + bj);
  }
}

// ---------------- Kernel 2: GRU scan, one block (CU) per batch element -----
// 1024 threads = 16 waves (4/SIMD -> 128-VGPR budget).
// Thread (j = tid&255, kq = tid>>8) holds the kq-th QUARTER (K=64) of column
// j of ALL THREE U matrices: 3 * 32 = 96 packed fp16 words. Fits in 128 VGPRs
// by construction -> no spill, no remat. Partials reduced via LDS.
__global__
__attribute__((amdgpu_flat_work_group_size(1024, 1024), amdgpu_waves_per_eu(4, 4)))
void k_scan(
    const float* __restrict__ h0,
    const float* __restrict__ Uz, const float* __restrict__ Ur,
    const float* __restrict__ Uh,
    const _Float16* __restrict__ Gzr, const _Float16* __restrict__ Gh,
    float* __restrict__ hs)
{
  __shared__ __align__(16) _Float16 h_h[H_];     // h_t as fp16
  __shared__ __align__(16) _Float16 rh_h[H_];    // r*h as fp16
  __shared__ float h_f[H_];                      // h_t as fp32
  __shared__ float zp[4][H_];                    // z partials / reused for h-gate
  __shared__ float rp[4][H_];                    // r partials

  const int b = blockIdx.x;
  const int tid = threadIdx.x;
  const int j = tid & 255;
  const int kq = tid >> 8;           // quarter index 0..3
  const int k0 = kq * 64;            // k-range [k0, k0+64)

  // ---- load U quarter-columns: 32 packed words each for Uz, Ur, Uh ----
  unsigned int uz[32], ur[32], uh[32];
#pragma unroll
  for (int m = 0; m < 32; ++m) {
    int k = k0 + 2 * m;
    {
      float a = Uz[(size_t)k * H_ + j], c = Uz[(size_t)(k + 1) * H_ + j];
      h2_t p; p[0] = (_Float16)a; p[1] = (_Float16)c;
      uz[m] = __builtin_bit_cast(unsigned int, p);
    }
    {
      float a = Ur[(size_t)k * H_ + j], c = Ur[(size_t)(k + 1) * H_ + j];
      h2_t p; p[0] = (_Float16)a; p[1] = (_Float16)c;
      ur[m] = __builtin_bit_cast(unsigned int, p);
    }
    {
      float a = Uh[(size_t)k * H_ + j], c = Uh[(size_t)(k + 1) * H_ + j];
      h2_t p; p[0] = (_Float16)a; p[1] = (_Float16)c;
      uh[m] = __builtin_bit_cast(unsigned int, p);
    }
  }
#pragma unroll
  for (int m = 0; m < 32; ++m) {
    asm volatile("" : "+v"(uz[m]));
    asm volatile("" : "+v"(ur[m]));
    asm volatile("" : "+v"(uh[m]));
  }

  // ---- init h ----
  float hreg = 0.f;                  // live in threads tid<256 (the j-owners)
  if (tid < H_) {
    hreg = h0[(size_t)b * H_ + tid];
    h_f[tid] = hreg;
    h_h[tid] = (_Float16)hreg;
  }
  __syncthreads();

  // ---- G pointers ----
  // tid<512: Gzr column (which*256+j) == tid. tid<256 additionally reads Gh.
  const _Float16* Gzr_p = Gzr + (size_t)b * T_ * 512 + tid;     // valid tid<512
  const _Float16* Gh_p  = Gh  + (size_t)b * T_ * H_ + j;        // valid tid<256
  float g_zr = 0.f, g_h = 0.f;
  if (tid < 512) g_zr = (float)Gzr_p[0];
  if (tid < 256) g_h  = (float)Gh_p[0];

  float* hsb = hs + (size_t)b * T_ * H_;
  float zreg = 0.f;                  // z gate, lives in tid<256

  const uint4* hq4  = (const uint4*)h_h  + kq * 8;   // this thread's h slice
  const uint4* rhq4 = (const uint4*)rh_h + kq * 8;   // this thread's rh slice

#pragma unroll 1
  for (int t = 0; t < T_; ++t) {
    const float gv_zr = g_zr;
    const float gv_h  = g_h;
    const int tn = (t + 1 < T_) ? (t + 1) : t;
    if (tid < 512) g_zr = (float)Gzr_p[tn * 512];    // prefetch next step
    if (tid < 256) g_h  = (float)Gh_p[tn * H_];

    // ---- phase 1: z and r quarter-dots against h (all 1024 threads) ----
    {
      float za0 = 0.f, za1 = 0.f, za2 = 0.f, za3 = 0.f;
      float ra0 = 0.f, ra1 = 0.f, ra2 = 0.f, ra3 = 0.f;
#pragma unroll
      for (int m = 0; m < 8; ++m) {
        uint4 hq = hq4[m];
        za0 = fdot2a(uz[4 * m + 0], hq.x, za0);
        za1 = fdot2a(uz[4 * m + 1], hq.y, za1);
        za2 = fdot2a(uz[4 * m + 2], hq.z, za2);
        za3 = fdot2a(uz[4 * m + 3], hq.w, za3);
        ra0 = fdot2a(ur[4 * m + 0], hq.x, ra0);
        ra1 = fdot2a(ur[4 * m + 1], hq.y, ra1);
        ra2 = fdot2a(ur[4 * m + 2], hq.z, ra2);
        ra3 = fdot2a(ur[4 * m + 3], hq.w, ra3);
      }
      zp[kq][j] = (za0 + za1) + (za2 + za3);
      rp[kq][j] = (ra0 + ra1) + (ra2 + ra3);
    }
    __syncthreads();

    // ---- phase 1b: reduce + gate nonlinearities (tid<512) ----
    if (tid < 512) {
      const float* P = (tid < 256) ? &zp[0][0] : &rp[0][0];
      float s4 = (P[j] + P[H_ + j]) + (P[2 * H_ + j] + P[3 * H_ + j]);
      float e = __expf(-(gv_zr + s4));
      float s = __builtin_amdgcn_rcpf(1.f + e);      // sigmoid
      if (tid < 256) {
        zreg = s;                                    // keep z in register
      } else {
        rh_h[j] = (_Float16)(s * h_f[j]);            // r * h
      }
    }
    __syncthreads();

    // ---- phase 2: h-gate quarter-dots against r*h (all 1024 threads) ----
    {
      float ha0 = 0.f, ha1 = 0.f, ha2 = 0.f, ha3 = 0.f;
#pragma unroll
      for (int m = 0; m < 8; ++m) {
        uint4 hq = rhq4[m];
        ha0 = fdot2a(uh[4 * m + 0], hq.x, ha0);
        ha1 = fdot2a(uh[4 * m + 1], hq.y, ha1);
        ha2 = fdot2a(uh[4 * m + 2], hq.z, ha2);
        ha3 = fdot2a(uh[4 * m + 3], hq.w, ha3);
      }
      zp[kq][j] = (ha0 + ha1) + (ha2 + ha3);         // reuse zp for h partials
    }
    __syncthreads();

    // ---- phase 2b: reduce + tanh + blend + emit (tid<256) ----
    if (tid < 256) {
      const float* P = &zp[0][0];
      float s4 = (P[j] + P[H_ + j]) + (P[2 * H_ + j] + P[3 * H_ + j]);
      float xh = gv_h + s4;
      float e = __expf(-2.f * xh);
      float hh = 2.f * __builtin_amdgcn_rcpf(1.f + e) - 1.f;   // tanh
      float hn = (1.f - zreg) * hreg + zreg * hh;
      hreg = hn;
      h_f[j] = hn;
      h_h[j] = (_Float16)hn;
      hsb[t * H_ + j] = hn;
    }
    __syncthreads();
  }
}

// ---------------- Kernel 3: ys = hs @ Wo + bo ------------------------------
__global__ __launch_bounds__(256) void k_out(
    const float* __restrict__ hs, const float* __restrict__ Wo,
    const float* __restrict__ bo, float* __restrict__ ys)
{
  __shared__ __align__(16) float sh[32][H_];
  const int row0 = blockIdx.x * 32;
  const int tid = threadIdx.x;

  const float4* hg = (const float4*)(hs + (size_t)row0 * H_);
  float4* sh4 = (float4*)&sh[0][0];
#pragma unroll
  for (int m = 0; m < 8; ++m) sh4[tid + 256 * m] = hg[tid + 256 * m];
  __syncthreads();

  const int j = tid;
  float acc[32];
#pragma unroll
  for (int i = 0; i < 32; ++i) acc[i] = 0.f;

#pragma unroll 2
  for (int k4 = 0; k4 < H_ / 4; ++k4) {
    float w0 = Wo[(size_t)(4 * k4 + 0) * DOUT + j];
    float w1 = Wo[(size_t)(4 * k4 + 1) * DOUT + j];
    float w2 = Wo[(size_t)(4 * k4 + 2) * DOUT + j];
    float w3 = Wo[(size_t)(4 * k4 + 3) * DOUT + j];
#pragma unroll
    for (int i = 0; i < 32; ++i) {
      float4 hv = *(const float4*)&sh[i][4 * k4];
      acc[i] = fmaf(hv.x, w0, acc[i]);
      acc[i] = fmaf(hv.y, w1, acc[i]);
      acc[i] = fmaf(hv.z, w2, acc[i]);
      acc[i] = fmaf(hv.w, w3, acc[i]);
    }
  }

  const float bj = bo[j];
  float* yp = ys + (size_t)row0 * DOUT + j;
#pragma unroll
  for (int i = 0; i < 32; ++i) yp[(size_t)i * DOUT] = acc[i] + bj;
}

// ---------------------------------------------------------------------------
extern "C" void kernel_launch(void* const* d_in, const int* in_sizes, int n_in,
                              void* d_out, int out_size, void* d_ws, size_t ws_size,
                              hipStream_t stream) {
  const float* x  = (const float*)d_in[0];
  const float* h0 = (const float*)d_in[1];
  const float* Wz = (const float*)d_in[2];
  const float* Uz = (const float*)d_in[3];
  const float* bz = (const float*)d_in[4];
  const float* Wr = (const float*)d_in[5];
  const float* Ur = (const float*)d_in[6];
  const float* br = (const float*)d_in[7];
  const float* Wh = (const float*)d_in[8];
  const float* Uh = (const float*)d_in[9];
  const float* bh = (const float*)d_in[10];
  const float* Wo = (const float*)d_in[11];
  const float* bo = (const float*)d_in[12];

  float* ys = (float*)d_out;
  float* hsO = ys + (size_t)B_ * T_ * DOUT;  // second output, written by scan

  _Float16* Gzr = (_Float16*)d_out;          // 64 MB, dead until k_out
  _Float16* Gh  = (_Float16*)d_ws;           // 32 MB in workspace

  dim3 g1((B_ * T_) / 32, 3);
  k_gates<<<g1, 256, 0, stream>>>(x, Wz, Wr, Wh, bz, br, bh, Gzr, Gh);
  k_scan<<<B_, 1024, 0, stream>>>(h0, Uz, Ur, Uh, Gzr, Gh, hsO);
  k_out<<<(B_ * T_) / 32, 256, 0, stream>>>(hsO, Wo, bo, ys);
}